// Round 10
// baseline (151.147 us; speedup 1.0000x reference)
//
#include <hip/hip_runtime.h>
#include <hip/hip_bf16.h>

#define T_STEPS 11
#define E_DIM   100
#define XSL     2048   // bytes per staged x slice: 128 chunks x 16 B (plain row-major)
#define NDMA    (2 * T_STEPS)   // 22 wave-DMAs (2 per slice)

typedef int   i32x4   __attribute__((ext_vector_type(4)));
typedef int   i32x8   __attribute__((ext_vector_type(8)));
typedef float f32x4   __attribute__((ext_vector_type(4)));
typedef _Float16 h16x2 __attribute__((ext_vector_type(2)));
typedef _Float16 h16x4 __attribute__((ext_vector_type(4)));
typedef _Float16 h16x8 __attribute__((ext_vector_type(8)));

typedef __attribute__((address_space(1))) const unsigned int g_as1;
typedef __attribute__((address_space(3))) unsigned int l_as3;

__device__ __forceinline__ h16x2 spl2(float v) {
    _Float16 h = (_Float16)v;
    return (h16x2){h, h};
}
__device__ __forceinline__ h16x2 pk2(float a, float b) {
    return __builtin_bit_cast(h16x2, __builtin_amdgcn_cvt_pkrtz(a, b));
}
__device__ __forceinline__ unsigned char f2fp8(float f) {
    return (unsigned char)(__builtin_amdgcn_cvt_pk_fp8_f32(f, 0.f, 0, false) & 0xff);
}
__device__ __forceinline__ long long ll_lo(i32x4 v) {
    return ((long long)(unsigned)v[1] << 32) | (unsigned)v[0];
}
__device__ __forceinline__ long long ll_hi(i32x4 v) {
    return ((long long)(unsigned)v[3] << 32) | (unsigned)v[2];
}

// deg-5 tanh (g-gate): x*(1 - x^2/3 + 2x^4/15)
__device__ __forceinline__ h16x2 tanh5(h16x2 x) {
    h16x2 x2 = x * x;
    h16x2 p = x2 * spl2(0.13333333f) + spl2(-0.33333333f);
    p = x2 * p + spl2(1.0f);
    return x * p;
}
// deg-7 tanh (tanh(c))
__device__ __forceinline__ h16x2 tanh7(h16x2 x) {
    h16x2 x2 = x * x;
    h16x2 p = x2 * spl2(-0.05396825f) + spl2(0.13333333f);
    p = x2 * p + spl2(-0.33333333f);
    p = x2 * p + spl2(1.0f);
    return x * p;
}
// deg-3 sigmoid: 0.5 + 0.25x - x^3/48
__device__ __forceinline__ h16x2 sig3(h16x2 x) {
    h16x2 x2 = x * x;
    h16x2 p = x2 * spl2(-0.020833334f) + spl2(0.25f);
    return x * p + spl2(0.5f);
}

// Pack:
//  blocks [0,128)   : W_ih (256x100 -> k-pad 128) fp8, MX K=128 A-fragment
//                     order: [mt][lane = m | (k>>5)<<4][k&31]  (32 B/lane)
//  blocks [128,192) : W_hh (256x64) fp8, 16x16x32 A-fragment order (unchanged)
//  block  192       : bias f32 = b_ih + b_hh
//  blocks [193,...) : emb f32[V][100] -> fp8[V][128] PLAIN row-major
__global__ void pack_all(const float* __restrict__ emb,
                         const float* __restrict__ W_ih, const float* __restrict__ W_hh,
                         const float* __restrict__ b_ih, const float* __restrict__ b_hh,
                         unsigned char* __restrict__ embp8, unsigned char* __restrict__ Wx8,
                         unsigned char* __restrict__ Wh8, float* __restrict__ biasf, int V)
{
    int b = blockIdx.x;
    int tid = threadIdx.x;
    if (b < 128) {
        int id = b * 256 + tid;
        int n = id >> 7, k = id & 127;
        float v = (k < E_DIM) ? W_ih[n * E_DIM + k] : 0.f;
        int mt = n >> 4;
        int lane = (n & 15) | ((k >> 5) << 4);
        Wx8[(mt * 64 + lane) * 32 + (k & 31)] = f2fp8(v);
    } else if (b < 192) {
        int id = (b - 128) * 256 + tid;
        int n = id >> 6, k = id & 63;
        int kt = k >> 5;
        int lane = (n & 15) | (((k & 31) >> 3) << 4);
        Wh8[((kt * 16 + (n >> 4)) * 64 + lane) * 8 + (k & 7)] = f2fp8(W_hh[n * 64 + k]);
    } else if (b == 192) {
        biasf[tid] = b_ih[tid] + b_hh[tid];
    } else {
        int id = (b - 193) * 256 + tid;
        if (id >= V * 8) return;
        int row = id >> 3;
        int c8 = id & 7;                 // 16-B chunk: k in [c8*16, +16)
        const float* xr = emb + (size_t)row * E_DIM;
        float v[16];
        #pragma unroll
        for (int w = 0; w < 16; ++w) {
            int k = c8 * 16 + w;
            v[w] = (k < E_DIM) ? xr[k] : 0.f;
        }
        int4 o;
        int* op = &o.x;
        #pragma unroll
        for (int w = 0; w < 4; ++w) {
            int d = __builtin_amdgcn_cvt_pk_fp8_f32(v[w*4+0], v[w*4+1], 0, false);
            d = __builtin_amdgcn_cvt_pk_fp8_f32(v[w*4+2], v[w*4+3], d, true);
            op[w] = d;
        }
        *reinterpret_cast<int4*>(embp8 + (size_t)row * 128 + c8 * 16) = o;
    }
}

// Block = 4 waves owns 16 batch rows. x-path: MX-scaled fp8 K=128 — 4 MFMAs
// per step (unit scales; arithmetic identical to non-scaled fp8). h-path:
// proven non-scaled fp8 16x16x32 (8 MFMAs). Per-step MFMA pipe demand
// 466 -> 293 cyc/SIMD. s_setprio elevates the recurrence-critical section.
// Regs: wx 32 + wh 16 + acc 16 = 64 AGPR -> 4 waves/SIMD with VGPR<=64.
template<int PACKED>
__global__ __launch_bounds__(256, 4)
void lstm_fused(const int* __restrict__ sent,
                const float* __restrict__ emb, const unsigned char* __restrict__ embp8,
                const unsigned char* __restrict__ Wx8, const unsigned char* __restrict__ Wh8,
                const float* __restrict__ biasf,
                const float* __restrict__ fc_W, const float* __restrict__ fc_b,
                float* __restrict__ out)
{
    __shared__ unsigned char xlds[T_STEPS * XSL];   // 22528 B
    __shared__ unsigned char hlds[2][1024];         // fp8 h tiles
    __shared__ float biaslds[256];
    __shared__ short hscr[16 * 68];                 // final h in f16 for FC
    const int tid  = threadIdx.x;
    const int wv   = tid >> 6;
    const int lane = tid & 63;
    const int r    = lane & 15;   // C col = batch row
    const int q    = lane >> 4;   // quad
    const int b0   = blockIdx.x * 16;

    // ---- stage all 11 x slices: 22 wave-DMAs (or manual cvt fallback) ----
    for (int d = wv; d < NDMA; d += 4) {
        int sl = d >> 1, half = d & 1;
        int c  = half * 4 + (lane >> 4);   // chunk 0..7
        int rr = lane & 15;
        int idx = sent[(b0 + rr) * T_STEPS + sl];
        if (PACKED) {
            const unsigned char* src = embp8 + (size_t)idx * 128 + c * 16;
            __builtin_amdgcn_global_load_lds(
                (g_as1*)src, (l_as3*)&xlds[sl * XSL + half * 1024], 16, 0, 0);
        } else {
            const float* xr = emb + (size_t)idx * E_DIM;
            float v[16];
            #pragma unroll
            for (int w = 0; w < 16; ++w) {
                int k = c * 16 + w;
                v[w] = (k < E_DIM) ? xr[k] : 0.f;
            }
            int4 o;
            int* op = &o.x;
            #pragma unroll
            for (int w = 0; w < 4; ++w) {
                int dd = __builtin_amdgcn_cvt_pk_fp8_f32(v[w*4+0], v[w*4+1], 0, false);
                dd = __builtin_amdgcn_cvt_pk_fp8_f32(v[w*4+2], v[w*4+3], dd, true);
                op[w] = dd;
            }
            *reinterpret_cast<int4*>(&xlds[sl * XSL + (c * 16 + rr) * 16]) = o;
        }
    }

    // ---- weight A-fragments -> registers (once) ----
    i32x8 wx[4];                 // MX K=128 frags: 4 m-tiles x 8 regs
    #pragma unroll
    for (int g = 0; g < 4; ++g)
        wx[g] = *reinterpret_cast<const i32x8*>(
            Wx8 + ((g * 4 + wv) * 64 + lane) * 32);
    long long wh[2][4];          // fp8 16x16x32 frags: 8 x 2 regs
    #pragma unroll
    for (int kt = 0; kt < 2; ++kt)
        #pragma unroll
        for (int g = 0; g < 4; ++g)
            wh[kt][g] = *reinterpret_cast<const long long*>(
                Wh8 + ((kt * 16 + g * 4 + wv) * 64 + lane) * 8);
    #pragma unroll
    for (int g = 0; g < 4; ++g)
        asm volatile("" : "+v"(wx[g]));
    #pragma unroll
    for (int kt = 0; kt < 2; ++kt)
        #pragma unroll
        for (int g = 0; g < 4; ++g)
            asm volatile("" : "+v"(wh[kt][g]));

    biaslds[tid] = biasf[tid];
    reinterpret_cast<int*>(&hlds[0][0])[tid] = 0;    // zero h buffer 0 (1024 B)

    __builtin_amdgcn_s_waitcnt(0);   // drain staging DMA + LDS writes
    __syncthreads();

    // acc = bias (broadcast f32 LDS read) + MX x-part of slice sl (4 MFMAs)
    auto acc_bias_x = [&](int sl, f32x4* acc) {
        #pragma unroll
        for (int g = 0; g < 4; ++g)
            acc[g] = *reinterpret_cast<const f32x4*>(
                &biaslds[(g * 4 + wv) * 16 + q * 4]);
        i32x4 lo = *reinterpret_cast<const i32x4*>(
            &xlds[sl * XSL + ((2 * q) * 16 + r) * 16]);
        i32x4 hi = *reinterpret_cast<const i32x4*>(
            &xlds[sl * XSL + ((2 * q + 1) * 16 + r) * 16]);
        i32x8 bx = { lo[0], lo[1], lo[2], lo[3], hi[0], hi[1], hi[2], hi[3] };
        #pragma unroll
        for (int g = 0; g < 4; ++g)
            acc[g] = __builtin_amdgcn_mfma_scale_f32_16x16x128_f8f6f4(
                wx[g], bx, acc[g], 0, 0, 0, 127, 0, 127);
    };

    h16x2 c01 = spl2(0.f), c23 = spl2(0.f);
    f32x4 acc[4];
    acc_bias_x(0, acc);

    // h write slot for this lane (constant over t)
    const int hq  = (wv & 1) * 2 + (q >> 1);
    const int hoff = (hq * 16 + r) * 16 + (wv >> 1) * 8 + (q & 1) * 4;

    #pragma unroll
    for (int t = 0; t < T_STEPS; ++t) {
        // 1. recurrence-critical (high prio): h read -> 8 h-MFMAs -> cell -> write
        __builtin_amdgcn_s_setprio(1);
        i32x4 hv = *reinterpret_cast<const i32x4*>(&hlds[t & 1][(q * 16 + r) * 16]);
        long long bh0 = ll_lo(hv), bh1 = ll_hi(hv);
        #pragma unroll
        for (int g = 0; g < 4; ++g)
            acc[g] = __builtin_amdgcn_mfma_f32_16x16x32_fp8_fp8(wh[0][g], bh0, acc[g], 0, 0, 0);
        #pragma unroll
        for (int g = 0; g < 4; ++g)
            acc[g] = __builtin_amdgcn_mfma_f32_16x16x32_fp8_fp8(wh[1][g], bh1, acc[g], 0, 0, 0);

        // 2. packed-f16 cell update: lane owns (batch r, h-cols wv*16+q*4+{0..3})
        h16x2 gi0 = pk2(acc[0][0], acc[0][1]), gi1 = pk2(acc[0][2], acc[0][3]);
        h16x2 gf0 = pk2(acc[1][0], acc[1][1]), gf1 = pk2(acc[1][2], acc[1][3]);
        h16x2 gg0 = pk2(acc[2][0], acc[2][1]), gg1 = pk2(acc[2][2], acc[2][3]);
        h16x2 go0 = pk2(acc[3][0], acc[3][1]), go1 = pk2(acc[3][2], acc[3][3]);
        c01 = sig3(gf0) * c01 + sig3(gi0) * tanh5(gg0);
        c23 = sig3(gf1) * c23 + sig3(gi1) * tanh5(gg1);
        h16x2 h01 = sig3(go0) * tanh7(c01);
        h16x2 h23 = sig3(go1) * tanh7(c23);

        int hw = __builtin_amdgcn_cvt_pk_fp8_f32((float)h01[0], (float)h01[1], 0, false);
        hw = __builtin_amdgcn_cvt_pk_fp8_f32((float)h23[0], (float)h23[1], hw, true);
        *reinterpret_cast<int*>(&hlds[(t + 1) & 1][hoff]) = hw;
        __builtin_amdgcn_s_setprio(0);

        if (t == T_STEPS - 1) {   // mirror final h in f16 for the FC tail
            h16x4 hn = { h01[0], h01[1], h23[0], h23[1] };
            *reinterpret_cast<h16x4*>(&hscr[r * 68 + wv * 16 + q * 4]) = hn;
        }

        // 3. barrier-shadow (low prio): bias + MX x-part of step t+1
        if (t + 1 < T_STEPS) acc_bias_x(t + 1, acc);

        __syncthreads();   // h_{t+1} visible; guards WAR on the other buffer
    }

    // ---- FC (14x64) + log_softmax; 16 rows, one per (wv,q) ----
    const int row_local = wv * 4 + q;
    const int cls = r;                      // 14 valid
    const int brow = b0 + row_local;
    float s = (cls < 14) ? fc_b[cls] : 0.f;
    const float* wrow = fc_W + ((cls < 14) ? cls : 0) * 64;
    #pragma unroll
    for (int ch = 0; ch < 8; ++ch) {
        h16x8 hv8 = *reinterpret_cast<const h16x8*>(&hscr[row_local * 68 + ch * 8]);
        #pragma unroll
        for (int j = 0; j < 8; ++j)
            s = fmaf((float)hv8[j], wrow[ch * 8 + j], s);
    }
    float lg = (cls < 14) ? s : -1e30f;
    float mx = lg;
    mx = fmaxf(mx, __shfl_xor(mx, 1));
    mx = fmaxf(mx, __shfl_xor(mx, 2));
    mx = fmaxf(mx, __shfl_xor(mx, 4));
    mx = fmaxf(mx, __shfl_xor(mx, 8));
    float se = __expf(lg - mx);
    se += __shfl_xor(se, 1);
    se += __shfl_xor(se, 2);
    se += __shfl_xor(se, 4);
    se += __shfl_xor(se, 8);
    float lse = mx + __logf(se);
    if (cls < 14) out[(size_t)brow * 14 + cls] = lg - lse;
}

extern "C" void kernel_launch(void* const* d_in, const int* in_sizes, int n_in,
                              void* d_out, int out_size, void* d_ws, size_t ws_size,
                              hipStream_t stream)
{
    const int*   sent = (const int*)d_in[0];
    const float* emb  = (const float*)d_in[1];
    const float* W_ih = (const float*)d_in[2];
    const float* W_hh = (const float*)d_in[3];
    const float* b_ih = (const float*)d_in[4];
    const float* b_hh = (const float*)d_in[5];
    const float* fc_W = (const float*)d_in[6];
    const float* fc_b = (const float*)d_in[7];
    float* out = (float*)d_out;

    const int B = in_sizes[0] / T_STEPS;               // 65536
    const int V = in_sizes[1] / E_DIM;                 // 50000
    const size_t emb_bytes = (size_t)V * 128;          // 6.4 MB
    const size_t need = emb_bytes + 32768 + 16384 + 1024;
    const bool packed = ws_size >= need;

    unsigned char* embp8 = (unsigned char*)d_ws;
    unsigned char* Wx8   = embp8 + emb_bytes;
    unsigned char* Wh8   = Wx8 + 32768;
    float*         biasf = (float*)(Wh8 + 16384);
    if (!packed) {
        Wx8   = (unsigned char*)d_ws;
        Wh8   = Wx8 + 32768;
        biasf = (float*)(Wh8 + 16384);
        embp8 = nullptr;
    }

    const int grid = B / 16;   // 4096
    if (packed) {
        int pgrid = 193 + (V * 8 + 255) / 256;
        pack_all<<<pgrid, 256, 0, stream>>>(emb, W_ih, W_hh, b_ih, b_hh,
                                            embp8, Wx8, Wh8, biasf, V);
        lstm_fused<1><<<grid, 256, 0, stream>>>(sent, emb, embp8, Wx8, Wh8,
                                                biasf, fc_W, fc_b, out);
    } else {
        pack_all<<<193, 256, 0, stream>>>(emb, W_ih, W_hh, b_ih, b_hh,
                                          nullptr, Wx8, Wh8, biasf, 0);
        lstm_fused<0><<<grid, 256, 0, stream>>>(sent, emb, nullptr, Wx8, Wh8,
                                                biasf, fc_W, fc_b, out);
    }
}